// Round 8
// baseline (440.682 us; speedup 1.0000x reference)
//
#include <hip/hip_runtime.h>
#include <hip/hip_bf16.h>

#define WIN 7
#define SHIFT_SZ 3
#define WSQ 49
#define CH 128
#define HW 56
#define LOG2E 1.4426950408889634f
#define QSCALE (0.17677669529663687f * LOG2E)

typedef short s16x8 __attribute__((ext_vector_type(8)));
typedef short s16x4 __attribute__((ext_vector_type(4)));
typedef float f32x4 __attribute__((ext_vector_type(4)));

static __device__ __forceinline__ f32x4 mfma16(s16x4 a, s16x4 b, f32x4 c) {
#if __has_builtin(__builtin_amdgcn_mfma_f32_16x16x16bf16_1k)
  return __builtin_amdgcn_mfma_f32_16x16x16bf16_1k(a, b, c, 0, 0, 0);
#else
  f32x4 d;
  asm("v_mfma_f32_16x16x16_bf16 %0, %1, %2, %3" : "=v"(d) : "v"(a), "v"(b), "v"(c));
  return d;
#endif
}

// ---------------- prep kernels ----------------

__global__ void prep_weights(const float* __restrict__ qkv_kernel,
                             const float* __restrict__ proj_kernel,
                             __hip_bfloat16* __restrict__ ws) {
  int idx = blockIdx.x * 256 + threadIdx.x;
  if (idx < 49152) {                      // WqkvT [384][128]
    int n = idx >> 7, c = idx & 127;
    ws[idx] = __float2bfloat16(qkv_kernel[c * 384 + n]);
  }
  if (idx < 16384) {                      // WprojT [128][128]
    int n = idx >> 7, c = idx & 127;
    ws[49152 + idx] = __float2bfloat16(proj_kernel[c * 128 + n]);
  }
}

// tbl[win][h][s][t] = LOG2E * (rel_pos_bias(s,t) + shift_mask(s,t));
// cols t>=49 -> -43280 (kills padded keys), rows s>=49 (dead queries) -> 0
__global__ void prep_tbl(const float* __restrict__ rel_pos_table,
                         __hip_bfloat16* __restrict__ tbl) {
  int idx = blockIdx.x * 256 + threadIdx.x;   // 2^20 total
  int t = idx & 63;
  int s = (idx >> 6) & 63;
  int h = (idx >> 12) & 3;
  int win = idx >> 14;
  float v;
  if (t >= WSQ) v = -43280.f;
  else if (s >= WSQ) v = 0.f;
  else {
    int i1 = s / 7, j1 = s % 7, i2 = t / 7, j2 = t % 7;
    int ridx = (i1 - i2 + 6) * 13 + (j1 - j2 + 6);
    float bias = rel_pos_table[ridx * 4 + h];
    int wy = win >> 3, wx = win & 7;
    int rh1 = (wy < 7) ? 0 : (i1 < 4 ? 1 : 2);
    int rh2 = (wy < 7) ? 0 : (i2 < 4 ? 1 : 2);
    int rw1 = (wx < 7) ? 0 : (j1 < 4 ? 1 : 2);
    int rw2 = (wx < 7) ? 0 : (j2 < 4 ? 1 : 2);
    float mask = (rh1 == rh2 && rw1 == rw2) ? 0.f : -100.f;
    v = (bias + mask) * LOG2E;
  }
  tbl[idx] = __float2bfloat16(v);
}

// ---------------- fused main kernel ----------------
// one block = one window (4096 blocks), 512 threads = 8 waves.
// Wave (h3, mh): computes its OWN Q (32 rows), and its head's FULL K and V
// (64x32) -- K/V MFMAs duplicated across the 2 row-half waves, in exchange
// for ZERO K/V LDS traffic: the x32 MFMA n-major acc (lane=token, reg=chan)
// is exactly the x16 QK^T A-operand; the m-major acc (lane=chan, reg=token)
// is exactly the x16 PV A-operand. Q and P are register-resident as before.
// LDS: [0,17408) x-stage [64][136] | [17408,34816) o [64][136]  (disjoint)
// Barriers: b1 (x staged) | b2 (o visible). Only 2.
// V-pass deferred until after softmax to cap register liveness (~60 arch).

__launch_bounds__(512, 6)
__global__ void swin_attn(const float* __restrict__ x,
                          const float* __restrict__ qkv_bias,
                          const float* __restrict__ proj_bias,
                          const __hip_bfloat16* __restrict__ wqkvT,
                          const __hip_bfloat16* __restrict__ wprojT,
                          const __hip_bfloat16* __restrict__ tbl,
                          float* __restrict__ out) {
  __shared__ __align__(16) char smem[34816];
  __hip_bfloat16* a_lds = (__hip_bfloat16*)smem;             // [64][136]
  __hip_bfloat16* o_lds = (__hip_bfloat16*)(smem + 17408);   // [64][136]

  const int tid = threadIdx.x;
  const int lane = tid & 63;
  const int wv = tid >> 6;          // wave 0..7
  const int g = lane >> 4;          // quarter-wave group
  const int c = lane & 15;

  const int widx = blockIdx.x;
  const int b  = widx >> 6;
  const int wy = (widx >> 3) & 7;
  const int wx = widx & 7;
  const int win64 = widx & 63;

  const int h3 = wv >> 1;           // attention head of this wave
  const int mh = wv & 1;            // s-half (rows 32*mh..32*mh+31)

  // ---- phase 1: stage shifted x-window as bf16 (rows 49..63 zero) ----
  for (int it = tid; it < 1024; it += 512) {
    int s = it >> 4;
    int l16 = it & 15;
    union { s16x8 v; __hip_bfloat16 h[8]; } u;
    if (s < WSQ) {
      int i = s / 7, j = s - i * 7;
      int hh = wy * 7 + i + SHIFT_SZ; if (hh >= HW) hh -= HW;
      int ww = wx * 7 + j + SHIFT_SZ; if (ww >= HW) ww -= HW;
      const float4* src = (const float4*)(x + (((b * HW + hh) * HW + ww) * CH + l16 * 8));
      float4 f0 = src[0], f1 = src[1];
      u.h[0] = __float2bfloat16(f0.x); u.h[1] = __float2bfloat16(f0.y);
      u.h[2] = __float2bfloat16(f0.z); u.h[3] = __float2bfloat16(f0.w);
      u.h[4] = __float2bfloat16(f1.x); u.h[5] = __float2bfloat16(f1.y);
      u.h[6] = __float2bfloat16(f1.z); u.h[7] = __float2bfloat16(f1.w);
    } else {
      #pragma unroll
      for (int q = 0; q < 8; ++q) u.h[q] = __float2bfloat16(0.f);
    }
    *(s16x8*)(a_lds + s * 136 + l16 * 8) = u.v;
  }
  __syncthreads();   // b1

  // ---- K-pass: head h3's full K (64 tok x 32 d), n-major, reg-resident ----
  // acc/kf16[kb][mt]: lane c = token 16mt+c, regs = d = 16kb+4g+r
  s16x4 kf16[2][4];
  {
    f32x4 acc[2][4];
    #pragma unroll
    for (int kb = 0; kb < 2; ++kb)
      #pragma unroll
      for (int mt = 0; mt < 4; ++mt) acc[kb][mt] = (f32x4){0.f, 0.f, 0.f, 0.f};
    #pragma unroll
    for (int kt = 0; kt < 4; ++kt) {
      s16x8 af[4];
      #pragma unroll
      for (int mt = 0; mt < 4; ++mt)
        af[mt] = *(const s16x8*)(a_lds + (16 * mt + c) * 136 + kt * 32 + g * 8);
      #pragma unroll
      for (int kb = 0; kb < 2; ++kb) {
        s16x8 bf = *(const s16x8*)(wqkvT + (128 + 32 * h3 + 16 * kb + c) * 128 + kt * 32 + g * 8);
        #pragma unroll
        for (int mt = 0; mt < 4; ++mt)
          acc[kb][mt] = __builtin_amdgcn_mfma_f32_16x16x32_bf16(bf, af[mt], acc[kb][mt], 0, 0, 0);
      }
    }
    #pragma unroll
    for (int kb = 0; kb < 2; ++kb) {
      float4 kb4 = *(const float4*)(qkv_bias + 128 + 32 * h3 + 16 * kb + 4 * g);
      #pragma unroll
      for (int mt = 0; mt < 4; ++mt) {
        union { s16x4 v; __hip_bfloat16 h[4]; } u;
        u.h[0] = __float2bfloat16(acc[kb][mt][0] + kb4.x);
        u.h[1] = __float2bfloat16(acc[kb][mt][1] + kb4.y);
        u.h[2] = __float2bfloat16(acc[kb][mt][2] + kb4.z);
        u.h[3] = __float2bfloat16(acc[kb][mt][3] + kb4.w);
        kf16[kb][mt] = u.v;
      }
    }
  }

  // ---- Q-pass: own 32 rows, n-major, reg-resident ----
  // qf16[kb][m]: lane c = token 32mh+16m+c, regs = d = 16kb+4g+r
  s16x4 qf16[2][2];
  {
    f32x4 acc[2][2];
    #pragma unroll
    for (int kb = 0; kb < 2; ++kb)
      #pragma unroll
      for (int m = 0; m < 2; ++m) acc[kb][m] = (f32x4){0.f, 0.f, 0.f, 0.f};
    #pragma unroll
    for (int kt = 0; kt < 4; ++kt) {
      s16x8 afq[2];
      #pragma unroll
      for (int m = 0; m < 2; ++m)
        afq[m] = *(const s16x8*)(a_lds + (16 * (2 * mh + m) + c) * 136 + kt * 32 + g * 8);
      #pragma unroll
      for (int kb = 0; kb < 2; ++kb) {
        s16x8 bf = *(const s16x8*)(wqkvT + (32 * h3 + 16 * kb + c) * 128 + kt * 32 + g * 8);
        #pragma unroll
        for (int m = 0; m < 2; ++m)
          acc[kb][m] = __builtin_amdgcn_mfma_f32_16x16x32_bf16(bf, afq[m], acc[kb][m], 0, 0, 0);
      }
    }
    #pragma unroll
    for (int kb = 0; kb < 2; ++kb) {
      float4 qb4 = *(const float4*)(qkv_bias + 32 * h3 + 16 * kb + 4 * g);
      #pragma unroll
      for (int m = 0; m < 2; ++m) {
        union { s16x4 v; __hip_bfloat16 h[4]; } u;
        u.h[0] = __float2bfloat16((acc[kb][m][0] + qb4.x) * QSCALE);
        u.h[1] = __float2bfloat16((acc[kb][m][1] + qb4.y) * QSCALE);
        u.h[2] = __float2bfloat16((acc[kb][m][2] + qb4.z) * QSCALE);
        u.h[3] = __float2bfloat16((acc[kb][m][3] + qb4.w) * QSCALE);
        qf16[kb][m] = u.v;
      }
    }
  }

  // ---- QK^T (pure-register x16 MFMA) + in-register softmax -> pf16 ----
  s16x4 pf16[2][4];   // [m][nt]: lane c = s-row, regs = t = 16nt+4g+r
  #pragma unroll
  for (int m = 0; m < 2; ++m) {
    f32x4 sc[4];
    #pragma unroll
    for (int nt = 0; nt < 4; ++nt) {
      sc[nt] = (f32x4){0.f, 0.f, 0.f, 0.f};
      #pragma unroll
      for (int kb = 0; kb < 2; ++kb)
        sc[nt] = mfma16(kf16[kb][nt], qf16[kb][m], sc[nt]);
    }
    const __hip_bfloat16* tb_ =
        tbl + (((win64 << 2) + h3) << 12) + (32 * mh + 16 * m + c) * 64;
    #pragma unroll
    for (int nt = 0; nt < 4; ++nt) {
      union { s16x4 v; __hip_bfloat16 h[4]; } tv;
      tv.v = *(const s16x4*)(tb_ + 16 * nt + 4 * g);
      #pragma unroll
      for (int r = 0; r < 4; ++r) sc[nt][r] += __bfloat162float(tv.h[r]);
    }
    float mx = -1e30f;
    #pragma unroll
    for (int nt = 0; nt < 4; ++nt)
      #pragma unroll
      for (int r = 0; r < 4; ++r) mx = fmaxf(mx, sc[nt][r]);
    mx = fmaxf(mx, __shfl_xor(mx, 16));
    mx = fmaxf(mx, __shfl_xor(mx, 32));
    float sum = 0.f;
    #pragma unroll
    for (int nt = 0; nt < 4; ++nt)
      #pragma unroll
      for (int r = 0; r < 4; ++r) {
        float e = __builtin_amdgcn_exp2f(sc[nt][r] - mx);
        sc[nt][r] = e;
        sum += e;
      }
    sum += __shfl_xor(sum, 16);
    sum += __shfl_xor(sum, 32);
    float inv = __builtin_amdgcn_rcpf(sum);
    #pragma unroll
    for (int nt = 0; nt < 4; ++nt) {
      union { s16x4 v; __hip_bfloat16 h[4]; } u;
      #pragma unroll
      for (int r = 0; r < 4; ++r) u.h[r] = __float2bfloat16(sc[nt][r] * inv);
      pf16[m][nt] = u.v;
    }
  }

  // ---- V-pass (deferred; a_lds still valid): head's full V, m-major ----
  // vf16[vt][mt]: lane c = d = 16vt+c, regs = token = 16mt+4g+r
  s16x4 vf16[2][4];
  {
    f32x4 acc[2][4];
    #pragma unroll
    for (int vt = 0; vt < 2; ++vt)
      #pragma unroll
      for (int mt = 0; mt < 4; ++mt) acc[vt][mt] = (f32x4){0.f, 0.f, 0.f, 0.f};
    #pragma unroll
    for (int kt = 0; kt < 4; ++kt) {
      s16x8 af[4];
      #pragma unroll
      for (int mt = 0; mt < 4; ++mt)
        af[mt] = *(const s16x8*)(a_lds + (16 * mt + c) * 136 + kt * 32 + g * 8);
      #pragma unroll
      for (int vt = 0; vt < 2; ++vt) {
        s16x8 bv = *(const s16x8*)(wqkvT + (256 + 32 * h3 + 16 * vt + c) * 128 + kt * 32 + g * 8);
        #pragma unroll
        for (int mt = 0; mt < 4; ++mt)
          acc[vt][mt] = __builtin_amdgcn_mfma_f32_16x16x32_bf16(af[mt], bv, acc[vt][mt], 0, 0, 0);
      }
    }
    #pragma unroll
    for (int vt = 0; vt < 2; ++vt) {
      float vb = qkv_bias[256 + 32 * h3 + 16 * vt + c];
      #pragma unroll
      for (int mt = 0; mt < 4; ++mt) {
        union { s16x4 v; __hip_bfloat16 h[4]; } u;
        #pragma unroll
        for (int r = 0; r < 4; ++r) u.h[r] = __float2bfloat16(acc[vt][mt][r] + vb);
        vf16[vt][mt] = u.v;
      }
    }
  }

  // ---- PV (pure-register x16 MFMA): O^T, lane=s-token, regs=d ----
  #pragma unroll
  for (int m = 0; m < 2; ++m)
    #pragma unroll
    for (int vt = 0; vt < 2; ++vt) {
      f32x4 oacc = (f32x4){0.f, 0.f, 0.f, 0.f};
      #pragma unroll
      for (int nt = 0; nt < 4; ++nt)
        oacc = mfma16(vf16[vt][nt], pf16[m][nt], oacc);
      union { s16x4 v; __hip_bfloat16 h[4]; } u;
      #pragma unroll
      for (int r = 0; r < 4; ++r) u.h[r] = __float2bfloat16(oacc[r]);
      *(s16x4*)(o_lds + (32 * mh + 16 * m + c) * 136 + 32 * h3 + 16 * vt + 4 * g) = u.v;
    }
  __syncthreads();   // b2: o visible

  // ---- proj GEMM (n-major out -> float4 stores). wave owns n-tile wv ----
  {
    f32x4 pacc[4];
    #pragma unroll
    for (int mt = 0; mt < 4; ++mt) pacc[mt] = (f32x4){0.f, 0.f, 0.f, 0.f};
    #pragma unroll
    for (int kt = 0; kt < 4; ++kt) {
      s16x8 bfp = *(const s16x8*)(wprojT + (16 * wv + c) * 128 + kt * 32 + g * 8);
      #pragma unroll
      for (int mt = 0; mt < 4; ++mt) {
        s16x8 afo = *(const s16x8*)(o_lds + (16 * mt + c) * 136 + kt * 32 + g * 8);
        pacc[mt] = __builtin_amdgcn_mfma_f32_16x16x32_bf16(bfp, afo, pacc[mt], 0, 0, 0);
      }
    }
    float4 pb4 = *(const float4*)(proj_bias + 16 * wv + 4 * g);
    #pragma unroll
    for (int mt = 0; mt < 4; ++mt) {
      int s = 16 * mt + c;
      if (s < WSQ) {
        int i = s / 7, j = s - i * 7;
        int hh = wy * 7 + i + SHIFT_SZ; if (hh >= HW) hh -= HW;
        int ww = wx * 7 + j + SHIFT_SZ; if (ww >= HW) ww -= HW;
        float4 v;
        v.x = pacc[mt][0] + pb4.x;
        v.y = pacc[mt][1] + pb4.y;
        v.z = pacc[mt][2] + pb4.z;
        v.w = pacc[mt][3] + pb4.w;
        *(float4*)(out + ((b * HW + hh) * HW + ww) * CH + 16 * wv + 4 * g) = v;
      }
    }
  }
}

extern "C" void kernel_launch(void* const* d_in, const int* in_sizes, int n_in,
                              void* d_out, int out_size, void* d_ws, size_t ws_size,
                              hipStream_t stream) {
  const float* x            = (const float*)d_in[0];
  const float* qkv_kernel   = (const float*)d_in[1];
  const float* qkv_bias     = (const float*)d_in[2];
  const float* proj_kernel  = (const float*)d_in[3];
  const float* proj_bias    = (const float*)d_in[4];
  const float* rel_pos_tbl  = (const float*)d_in[5];
  float* out = (float*)d_out;

  __hip_bfloat16* wsb    = (__hip_bfloat16*)d_ws;
  __hip_bfloat16* wqkvT  = wsb;            // 49152 elems
  __hip_bfloat16* wprojT = wsb + 49152;    // 16384 elems
  __hip_bfloat16* tbl    = wsb + 65536;    // 1048576 elems

  prep_weights<<<dim3(192), dim3(256), 0, stream>>>(qkv_kernel, proj_kernel, wsb);
  prep_tbl<<<dim3(4096), dim3(256), 0, stream>>>(rel_pos_tbl, tbl);
  swin_attn<<<dim3(4096), dim3(512), 0, stream>>>(x, qkv_bias, proj_bias,
                                                  wqkvT, wprojT, tbl, out);
}

// Round 9
// 126.848 us; speedup vs baseline: 3.4741x; 3.4741x over previous
//
#include <hip/hip_runtime.h>
#include <hip/hip_bf16.h>

#define WIN 7
#define SHIFT_SZ 3
#define WSQ 49
#define CH 128
#define HW 56
#define LOG2E 1.4426950408889634f
#define QSCALE (0.17677669529663687f * LOG2E)

typedef short s16x8 __attribute__((ext_vector_type(8)));
typedef short s16x4 __attribute__((ext_vector_type(4)));
typedef float f32x4 __attribute__((ext_vector_type(4)));

// ---------------- prep kernels ----------------

__global__ void prep_weights(const float* __restrict__ qkv_kernel,
                             const float* __restrict__ proj_kernel,
                             __hip_bfloat16* __restrict__ ws) {
  int idx = blockIdx.x * 256 + threadIdx.x;
  if (idx < 49152) {                      // WqkvT [384][128]
    int n = idx >> 7, c = idx & 127;
    ws[idx] = __float2bfloat16(qkv_kernel[c * 384 + n]);
  }
  if (idx < 16384) {                      // WprojT [128][128]
    int n = idx >> 7, c = idx & 127;
    ws[49152 + idx] = __float2bfloat16(proj_kernel[c * 128 + n]);
  }
}

// Only 4 distinct shift masks exist: cls = (wy==7)*2 + (wx==7).
// tbl[cls][h][s][t] = LOG2E * (rel_pos_bias(s,t) + mask(cls,s,t));
// cols t>=49 -> -43280 (kills padded keys), rows s>=49 (dead queries) -> 0
__global__ void prep_tbl(const float* __restrict__ rel_pos_table,
                         __hip_bfloat16* __restrict__ tbl) {
  int idx = blockIdx.x * 256 + threadIdx.x;   // 65536 total
  int t = idx & 63;
  int s = (idx >> 6) & 63;
  int h = (idx >> 12) & 3;
  int cls = idx >> 14;                        // 0..3
  float v;
  if (t >= WSQ) v = -43280.f;
  else if (s >= WSQ) v = 0.f;
  else {
    int i1 = s / 7, j1 = s % 7, i2 = t / 7, j2 = t % 7;
    int ridx = (i1 - i2 + 6) * 13 + (j1 - j2 + 6);
    float bias = rel_pos_table[ridx * 4 + h];
    int wyIs7 = cls >> 1, wxIs7 = cls & 1;
    int rh1 = wyIs7 ? (i1 < 4 ? 1 : 2) : 0;
    int rh2 = wyIs7 ? (i2 < 4 ? 1 : 2) : 0;
    int rw1 = wxIs7 ? (j1 < 4 ? 1 : 2) : 0;
    int rw2 = wxIs7 ? (j2 < 4 ? 1 : 2) : 0;
    float mask = (rh1 == rh2 && rw1 == rw2) ? 0.f : -100.f;
    v = (bias + mask) * LOG2E;
  }
  tbl[idx] = __float2bfloat16(v);
}

// ---------------- fused main kernel ----------------
// one block = one window (4096 blocks), 512 threads = 8 waves.
// LDS 53248 B (3 blocks/CU), time-multiplexed:
//   [0,16384)      a [64][128] XOR-swz          (phase 1-2)
//   [0,18432)      q [4][64][36]                (post-b2 .. b4)
//   [18432,36864)  k [4][64][36]                (pre-b2 .. b4)
//   [36864,53248)  vt [4][32][64] blk-swz       (pass A .. PV)
//   [0,32768)      p [4][64][64] XOR-swz        (post-b4, wave-local)
//   [36864,53248)  o [64][128] XOR-swz          (post-b5 .. proj)
// XOR swizzle: 16B-block index ^= (row & 7); every accessed row ≡ c (mod 8)
// for the accessing lane, so readers/writers agree on the mask. Kills the
// 4c+2g-pattern multi-way bank conflicts of the b64 scatters (8.9M in R2).

static __device__ __forceinline__ s16x8 ld2x64(const __hip_bfloat16* p) {
  s16x8 r;
  *(s16x4*)&r = *(const s16x4*)p;
  *(((s16x4*)&r) + 1) = *(const s16x4*)(p + 4);
  return r;
}

__launch_bounds__(512, 6)
__global__ void swin_attn(const float* __restrict__ x,
                          const float* __restrict__ qkv_bias,
                          const float* __restrict__ proj_bias,
                          const __hip_bfloat16* __restrict__ wqkvT,
                          const __hip_bfloat16* __restrict__ wprojT,
                          const __hip_bfloat16* __restrict__ tbl,
                          float* __restrict__ out) {
  __shared__ __align__(16) char smem[53248];
  __hip_bfloat16* a_lds  = (__hip_bfloat16*)smem;             // [64][128] swz
  __hip_bfloat16* q_lds  = (__hip_bfloat16*)smem;             // [4][64][36]
  __hip_bfloat16* k_lds  = (__hip_bfloat16*)(smem + 18432);   // [4][64][36]
  __hip_bfloat16* vt_lds = (__hip_bfloat16*)(smem + 36864);   // [4][32][64] swz
  __hip_bfloat16* p_lds  = (__hip_bfloat16*)smem;             // [4][64][64] swz
  __hip_bfloat16* o_lds  = (__hip_bfloat16*)(smem + 36864);   // [64][128] swz

  const int tid = threadIdx.x;
  const int lane = tid & 63;
  const int wv = tid >> 6;          // wave 0..7
  const int g = lane >> 4;          // quarter-wave group
  const int c = lane & 15;
  const int e = c & 7;              // XOR mask for rows ≡ c (mod 8)

  const int widx = blockIdx.x;
  const int b  = widx >> 6;
  const int wy = (widx >> 3) & 7;
  const int wx = widx & 7;
  const int mc = ((wy == 7) ? 2 : 0) + ((wx == 7) ? 1 : 0);

  // ---- phase 1: stage shifted x-window as bf16 (rows 49..63 zero) ----
  for (int it = tid; it < 1024; it += 512) {
    int s = it >> 4;
    int l16 = it & 15;
    union { s16x8 v; __hip_bfloat16 h[8]; } u;
    if (s < WSQ) {
      int i = s / 7, j = s - i * 7;
      int hh = wy * 7 + i + SHIFT_SZ; if (hh >= HW) hh -= HW;
      int ww = wx * 7 + j + SHIFT_SZ; if (ww >= HW) ww -= HW;
      const float4* src = (const float4*)(x + (((b * HW + hh) * HW + ww) * CH + l16 * 8));
      float4 f0 = src[0], f1 = src[1];
      u.h[0] = __float2bfloat16(f0.x); u.h[1] = __float2bfloat16(f0.y);
      u.h[2] = __float2bfloat16(f0.z); u.h[3] = __float2bfloat16(f0.w);
      u.h[4] = __float2bfloat16(f1.x); u.h[5] = __float2bfloat16(f1.y);
      u.h[6] = __float2bfloat16(f1.z); u.h[7] = __float2bfloat16(f1.w);
    } else {
      #pragma unroll
      for (int q = 0; q < 8; ++q) u.h[q] = __float2bfloat16(0.f);
    }
    *(s16x8*)(a_lds + s * 128 + ((l16 ^ (s & 7)) * 8)) = u.v;
  }
  __syncthreads();   // b1

  // ---- phase 2, pass A: V tile (n-tile 16+wv), m-major out ----
  {
    f32x4 acc_v[4];
    #pragma unroll
    for (int mt = 0; mt < 4; ++mt) acc_v[mt] = (f32x4){0.f, 0.f, 0.f, 0.f};
    #pragma unroll
    for (int kt = 0; kt < 4; ++kt) {
      s16x8 bv = *(const s16x8*)(wqkvT + (16 * (16 + wv) + c) * 128 + kt * 32 + g * 8);
      #pragma unroll
      for (int mt = 0; mt < 4; ++mt) {
        s16x8 af = *(const s16x8*)(a_lds + (16 * mt + c) * 128 + ((4 * kt + g) ^ e) * 8);
        acc_v[mt] = __builtin_amdgcn_mfma_f32_16x16x32_bf16(af, bv, acc_v[mt], 0, 0, 0);
      }
    }
    // scatter V^T: rows d, cols t; 8B packed, 16B-block swizzle
    int hv = wv >> 1;
    int d = (wv & 1) * 16 + c;
    float bvb = qkv_bias[256 + wv * 16 + c];
    __hip_bfloat16* vdst = vt_lds + (hv * 32 + d) * 64;
    #pragma unroll
    for (int mt = 0; mt < 4; ++mt) {
      union { s16x4 v; __hip_bfloat16 h[4]; } u;
      #pragma unroll
      for (int r = 0; r < 4; ++r) u.h[r] = __float2bfloat16(acc_v[mt][r] + bvb);
      *(s16x4*)(vdst + ((2 * mt + (g >> 1)) ^ e) * 8 + (g & 1) * 4) = u.v;
    }
  }

  // ---- phase 2, pass B: Q/K tiles {2wv, 2wv+1}, n-major out ----
  {
    f32x4 acc[2][4];
    #pragma unroll
    for (int ntl = 0; ntl < 2; ++ntl)
      #pragma unroll
      for (int mt = 0; mt < 4; ++mt) acc[ntl][mt] = (f32x4){0.f, 0.f, 0.f, 0.f};
    #pragma unroll
    for (int kt = 0; kt < 4; ++kt) {
      s16x8 af[4];
      #pragma unroll
      for (int mt = 0; mt < 4; ++mt)
        af[mt] = *(const s16x8*)(a_lds + (16 * mt + c) * 128 + ((4 * kt + g) ^ e) * 8);
      #pragma unroll
      for (int ntl = 0; ntl < 2; ++ntl) {
        s16x8 bf = *(const s16x8*)(wqkvT + (16 * (2 * wv + ntl) + c) * 128 + kt * 32 + g * 8);
        #pragma unroll
        for (int mt = 0; mt < 4; ++mt)
          acc[ntl][mt] = __builtin_amdgcn_mfma_f32_16x16x32_bf16(bf, af[mt], acc[ntl][mt], 0, 0, 0);
      }
    }
    const float scale = (wv < 4) ? QSCALE : 1.0f;
    // waves 4-7 own K tiles -> region disjoint from a_lds, scatter pre-barrier
    if (wv >= 4) {
      #pragma unroll
      for (int ntl = 0; ntl < 2; ++ntl) {
        int qt = 2 * wv + ntl;
        int h = (qt >> 1) & 3;
        int d0 = (qt & 1) * 16 + 4 * g;
        float4 b4 = *(const float4*)(qkv_bias + qt * 16 + 4 * g);
        __hip_bfloat16* dst = k_lds + h * 2304 + d0;
        #pragma unroll
        for (int mt = 0; mt < 4; ++mt) {
          union { s16x4 v; __hip_bfloat16 h[4]; } u;
          u.h[0] = __float2bfloat16((acc[ntl][mt][0] + b4.x) * scale);
          u.h[1] = __float2bfloat16((acc[ntl][mt][1] + b4.y) * scale);
          u.h[2] = __float2bfloat16((acc[ntl][mt][2] + b4.z) * scale);
          u.h[3] = __float2bfloat16((acc[ntl][mt][3] + b4.w) * scale);
          *(s16x4*)(dst + (16 * mt + c) * 36) = u.v;
        }
      }
    }
    __syncthreads();   // b2: all a_lds reads done
    if (wv < 4) {
      #pragma unroll
      for (int ntl = 0; ntl < 2; ++ntl) {
        int qt = 2 * wv + ntl;
        int h = (qt >> 1) & 3;
        int d0 = (qt & 1) * 16 + 4 * g;
        float4 b4 = *(const float4*)(qkv_bias + qt * 16 + 4 * g);
        __hip_bfloat16* dst = q_lds + h * 2304 + d0;
        #pragma unroll
        for (int mt = 0; mt < 4; ++mt) {
          union { s16x4 v; __hip_bfloat16 h[4]; } u;
          u.h[0] = __float2bfloat16((acc[ntl][mt][0] + b4.x) * scale);
          u.h[1] = __float2bfloat16((acc[ntl][mt][1] + b4.y) * scale);
          u.h[2] = __float2bfloat16((acc[ntl][mt][2] + b4.z) * scale);
          u.h[3] = __float2bfloat16((acc[ntl][mt][3] + b4.w) * scale);
          *(s16x4*)(dst + (16 * mt + c) * 36) = u.v;
        }
      }
    }
  }
  __syncthreads();   // b3: q/k/vt visible

  // ---- phase 3a: preload q/k fragments ----
  const int h3 = wv >> 1;
  const int mh = wv & 1;
  s16x8 qf[2], kf[4];
  #pragma unroll
  for (int m = 0; m < 2; ++m)
    qf[m] = ld2x64(q_lds + (h3 * 64 + 16 * (2 * mh + m) + c) * 36 + g * 8);
  #pragma unroll
  for (int nt = 0; nt < 4; ++nt)
    kf[nt] = ld2x64(k_lds + (h3 * 64 + 16 * nt + c) * 36 + g * 8);
  __syncthreads();   // b4: q/k reads done; p writes may clobber

  // ---- phase 3b: QK^T (t-major), in-register softmax, swizzled P write ----
  #pragma unroll
  for (int m = 0; m < 2; ++m) {
    f32x4 sc[4];
    #pragma unroll
    for (int nt = 0; nt < 4; ++nt) {
      sc[nt] = (f32x4){0.f, 0.f, 0.f, 0.f};
      sc[nt] = __builtin_amdgcn_mfma_f32_16x16x32_bf16(kf[nt], qf[m], sc[nt], 0, 0, 0);
    }
    const __hip_bfloat16* tb_ =
        tbl + (((mc << 2) + h3) << 12) + (32 * mh + 16 * m + c) * 64;
    #pragma unroll
    for (int nt = 0; nt < 4; ++nt) {
      union { s16x4 v; __hip_bfloat16 h[4]; } tv;
      tv.v = *(const s16x4*)(tb_ + 16 * nt + 4 * g);
      #pragma unroll
      for (int r = 0; r < 4; ++r) sc[nt][r] += __bfloat162float(tv.h[r]);
    }
    float mx = -1e30f;
    #pragma unroll
    for (int nt = 0; nt < 4; ++nt)
      #pragma unroll
      for (int r = 0; r < 4; ++r) mx = fmaxf(mx, sc[nt][r]);
    mx = fmaxf(mx, __shfl_xor(mx, 16));
    mx = fmaxf(mx, __shfl_xor(mx, 32));
    float sum = 0.f;
    #pragma unroll
    for (int nt = 0; nt < 4; ++nt)
      #pragma unroll
      for (int r = 0; r < 4; ++r) {
        float e2 = __builtin_amdgcn_exp2f(sc[nt][r] - mx);
        sc[nt][r] = e2;
        sum += e2;
      }
    sum += __shfl_xor(sum, 16);
    sum += __shfl_xor(sum, 32);
    float inv = __builtin_amdgcn_rcpf(sum);
    __hip_bfloat16* prow = p_lds + (h3 * 64 + 16 * (2 * mh + m) + c) * 64;
    #pragma unroll
    for (int nt = 0; nt < 4; ++nt) {
      union { s16x4 v; __hip_bfloat16 h[4]; } u;
      #pragma unroll
      for (int r = 0; r < 4; ++r) u.h[r] = __float2bfloat16(sc[nt][r] * inv);
      *(s16x4*)(prow + ((2 * nt + (g >> 1)) ^ e) * 8 + (g & 1) * 4) = u.v;
    }
  }

  // ---- PV: O = P @ V, swapped operands -> d-major out ----
  f32x4 oacc[2][2];
  #pragma unroll
  for (int m = 0; m < 2; ++m)
    #pragma unroll
    for (int ntd = 0; ntd < 2; ++ntd) oacc[m][ntd] = (f32x4){0.f, 0.f, 0.f, 0.f};
  #pragma unroll
  for (int kt = 0; kt < 2; ++kt) {
    s16x8 vfr[2], pfr[2];
    #pragma unroll
    for (int ntd = 0; ntd < 2; ++ntd)
      vfr[ntd] = *(const s16x8*)(vt_lds + (h3 * 32 + 16 * ntd + c) * 64 +
                                 (((4 * kt + g) ^ e) * 8));
    #pragma unroll
    for (int m = 0; m < 2; ++m)
      pfr[m] = *(const s16x8*)(p_lds + (h3 * 64 + 16 * (2 * mh + m) + c) * 64 +
                               (((4 * kt + g) ^ e) * 8));
    #pragma unroll
    for (int m = 0; m < 2; ++m)
      #pragma unroll
      for (int ntd = 0; ntd < 2; ++ntd)
        oacc[m][ntd] = __builtin_amdgcn_mfma_f32_16x16x32_bf16(vfr[ntd], pfr[m], oacc[m][ntd], 0, 0, 0);
  }
  __syncthreads();   // b5: p/vt reads done; o writes may clobber vt

  #pragma unroll
  for (int m = 0; m < 2; ++m)
    #pragma unroll
    for (int ntd = 0; ntd < 2; ++ntd) {
      union { s16x4 v; __hip_bfloat16 h[4]; } u;
      #pragma unroll
      for (int r = 0; r < 4; ++r) u.h[r] = __float2bfloat16(oacc[m][ntd][r]);
      *(s16x4*)(o_lds + (32 * mh + 16 * m + c) * 128 +
                ((4 * h3 + 2 * ntd + (g >> 1)) ^ e) * 8 + (g & 1) * 4) = u.v;
    }
  __syncthreads();   // b6: o visible

  // ---- phase 4: proj GEMM (n-major out -> float4 stores) ----
  {
    f32x4 pacc[4];
    #pragma unroll
    for (int mt = 0; mt < 4; ++mt) pacc[mt] = (f32x4){0.f, 0.f, 0.f, 0.f};
    #pragma unroll
    for (int kt = 0; kt < 4; ++kt) {
      s16x8 bfp = *(const s16x8*)(wprojT + (16 * wv + c) * 128 + kt * 32 + g * 8);
      #pragma unroll
      for (int mt = 0; mt < 4; ++mt) {
        s16x8 afo = *(const s16x8*)(o_lds + (16 * mt + c) * 128 + ((4 * kt + g) ^ e) * 8);
        pacc[mt] = __builtin_amdgcn_mfma_f32_16x16x32_bf16(bfp, afo, pacc[mt], 0, 0, 0);
      }
    }
    float4 pb4 = *(const float4*)(proj_bias + 16 * wv + 4 * g);
    #pragma unroll
    for (int mt = 0; mt < 4; ++mt) {
      int s = 16 * mt + c;
      if (s < WSQ) {
        int i = s / 7, j = s - i * 7;
        int hh = wy * 7 + i + SHIFT_SZ; if (hh >= HW) hh -= HW;
        int ww = wx * 7 + j + SHIFT_SZ; if (ww >= HW) ww -= HW;
        float4 v;
        v.x = pacc[mt][0] + pb4.x;
        v.y = pacc[mt][1] + pb4.y;
        v.z = pacc[mt][2] + pb4.z;
        v.w = pacc[mt][3] + pb4.w;
        *(float4*)(out + ((b * HW + hh) * HW + ww) * CH + 16 * wv + 4 * g) = v;
      }
    }
  }
}

extern "C" void kernel_launch(void* const* d_in, const int* in_sizes, int n_in,
                              void* d_out, int out_size, void* d_ws, size_t ws_size,
                              hipStream_t stream) {
  const float* x            = (const float*)d_in[0];
  const float* qkv_kernel   = (const float*)d_in[1];
  const float* qkv_bias     = (const float*)d_in[2];
  const float* proj_kernel  = (const float*)d_in[3];
  const float* proj_bias    = (const float*)d_in[4];
  const float* rel_pos_tbl  = (const float*)d_in[5];
  float* out = (float*)d_out;

  __hip_bfloat16* wsb    = (__hip_bfloat16*)d_ws;
  __hip_bfloat16* wqkvT  = wsb;            // 49152 elems
  __hip_bfloat16* wprojT = wsb + 49152;    // 16384 elems
  __hip_bfloat16* tbl    = wsb + 65536;    // 65536 elems (4 mask classes)

  prep_weights<<<dim3(192), dim3(256), 0, stream>>>(qkv_kernel, proj_kernel, wsb);
  prep_tbl<<<dim3(256), dim3(256), 0, stream>>>(rel_pos_tbl, tbl);
  swin_attn<<<dim3(4096), dim3(512), 0, stream>>>(x, qkv_bias, proj_bias,
                                                  wqkvT, wprojT, tbl, out);
}